// Round 1
// baseline (371.331 us; speedup 1.0000x reference)
//
#include <hip/hip_runtime.h>
#include <cstdint>
#include <cstddef>

typedef _Float16 f16;
typedef _Float16 f16x4 __attribute__((ext_vector_type(4)));
typedef _Float16 f16x8 __attribute__((ext_vector_type(8)));
typedef float f32x4 __attribute__((ext_vector_type(4)));

#define MFMA16(a,b,c) __builtin_amdgcn_mfma_f32_16x16x32_f16((a),(b),(c),0,0,0)

__device__ __forceinline__ void gload_lds16(const f16* g, f16* l) {
  __builtin_amdgcn_global_load_lds(
      (const __attribute__((address_space(1))) unsigned int*)g,
      (__attribute__((address_space(3))) unsigned int*)l, 16, 0, 0);
}

// ---------------- workspace layout (bytes) ----------------
static constexpr size_t OFF_TCPB = 0;                     // 3969*16*4 fp32
static constexpr size_t OFF_BIAS = 262144;                // 16*1024*1024 f16  [h][n>>2][m][n&3]
static constexpr size_t OFF_XHI  = OFF_BIAS + 33554432;   // 8192*512 f16
static constexpr size_t OFF_XLO  = OFF_XHI + 8388608;
static constexpr size_t OFF_WHI  = OFF_XLO + 8388608;     // 1536*512 f16
static constexpr size_t OFF_WLO  = OFF_WHI + 1572864;
static constexpr size_t OFF_PW   = OFF_WLO + 1572864;     // 512*512 f16
static constexpr size_t OFF_QHI  = OFF_PW  + 524288;      // [B][H][N][32] f16
static constexpr size_t OFF_QLO  = OFF_QHI + 8388608;
static constexpr size_t OFF_KHI  = OFF_QLO + 8388608;
static constexpr size_t OFF_KLO  = OFF_KHI + 8388608;
static constexpr size_t OFF_VT   = OFF_KLO + 8388608;     // [B][H][32][N] f16
static constexpr size_t OFF_AO   = OFF_VT  + 8388608;     // [8192][512] f16
// total = 96,206,848 bytes

// ---------------- kernel 1: fp32 -> f16 hi/lo splits ----------------
__global__ __launch_bounds__(256) void k_convert(
    const float* __restrict__ x, const float* __restrict__ qw, const float* __restrict__ pwf,
    f16* __restrict__ xhi, f16* __restrict__ xlo,
    f16* __restrict__ whi, f16* __restrict__ wlo, f16* __restrict__ pw)
{
  int i = blockIdx.x * 256 + threadIdx.x;     // 1,310,720 float4 groups total
  const float4* src; f16* dh; f16* dl; int j;
  if (i < 1048576)      { j = i;           src = (const float4*)x;   dh = xhi; dl = xlo; }
  else if (i < 1245184) { j = i - 1048576; src = (const float4*)qw;  dh = whi; dl = wlo; }
  else                  { j = i - 1245184; src = (const float4*)pwf; dh = pw;  dl = nullptr; }
  float4 v = src[j];
  f16x4 h;
  h[0] = (f16)v.x; h[1] = (f16)v.y; h[2] = (f16)v.z; h[3] = (f16)v.w;
  ((f16x4*)dh)[j] = h;
  if (dl) {
    f16x4 l;
    l[0] = (f16)(v.x - (float)h[0]); l[1] = (f16)(v.y - (float)h[1]);
    l[2] = (f16)(v.z - (float)h[2]); l[3] = (f16)(v.w - (float)h[3]);
    ((f16x4*)dl)[j] = l;
  }
}

// ---------------- kernel 2: CPB MLP -> t[3969][16] fp32 ----------------
__global__ __launch_bounds__(64) void k_cpb(
    const float* __restrict__ table, const float* __restrict__ w1, const float* __restrict__ b1,
    const float* __restrict__ w2, const float* __restrict__ b2, float* __restrict__ t_out)
{
  const int r = blockIdx.x;
  const int lane = threadIdx.x;
  const float c0 = table[2*r], c1 = table[2*r+1];
  const int j0 = lane * 8;
  float h[8];
#pragma unroll
  for (int jj = 0; jj < 8; jj++) {
    int j = j0 + jj;
    float v = c0 * w1[2*j] + c1 * w1[2*j+1] + b1[j];
    h[jj] = v > 0.0f ? v : 0.0f;
  }
  float acc[16];
#pragma unroll
  for (int o = 0; o < 16; o++) {
    const float4* wp = (const float4*)(w2 + o*512 + j0);
    float4 a = wp[0], bb = wp[1];
    acc[o] = a.x*h[0] + a.y*h[1] + a.z*h[2] + a.w*h[3]
           + bb.x*h[4] + bb.y*h[5] + bb.z*h[6] + bb.w*h[7];
  }
#pragma unroll
  for (int o = 0; o < 16; o++) {
    float v = acc[o];
    for (int s = 1; s < 64; s <<= 1) v += __shfl_xor(v, s, 64);
    acc[o] = v;
  }
  if (lane == 0) {
#pragma unroll
    for (int o = 0; o < 16; o++) t_out[r*16 + o] = acc[o] + b2[o];
  }
}

// ---------------- kernel 3: bias gather -> swizzled f16 [h][n>>2][m][n&3] ----------------
__global__ __launch_bounds__(256) void k_bias(
    const int* __restrict__ idx, const float* __restrict__ t_cpb, f16* __restrict__ bias_sw)
{
  int tid = blockIdx.x * 256 + threadIdx.x;   // 16 * 256 * 256 = 1,048,576
  int h = tid >> 16;
  int rest = tid & 65535;
  int n4 = rest >> 8, m4 = rest & 255;
  int4 I[4];
#pragma unroll
  for (int a = 0; a < 4; a++) I[a] = ((const int4*)(idx + (size_t)(n4*4 + a)*1024))[m4];
  f16 tmp[16];
#pragma unroll
  for (int c = 0; c < 4; c++) {
#pragma unroll
    for (int a = 0; a < 4; a++) {
      int id;
      if (c == 0) id = I[a].x; else if (c == 1) id = I[a].y;
      else if (c == 2) id = I[a].z; else id = I[a].w;
      tmp[c*4 + a] = (f16)t_cpb[id*16 + h];
    }
  }
  f16* outp = bias_sw + ((size_t)(h*256 + n4)*1024 + m4*4)*4;
  f16x8 r0, r1;
#pragma unroll
  for (int q = 0; q < 8; q++) { r0[q] = tmp[q]; r1[q] = tmp[8 + q]; }
  ((f16x8*)outp)[0] = r0;
  ((f16x8*)outp)[1] = r1;
}

// ---------------- kernel 4: QKV GEMM (split f16) + normalize epilogue ----------------
// x[8192][512] @ qkv_w[1536][512]^T ; cols 0..511 -> Q, 512..1023 -> K, 1024..1535 -> V
__global__ __launch_bounds__(256) void k_qkv(
    const f16* __restrict__ xhi, const f16* __restrict__ xlo,
    const f16* __restrict__ whi, const f16* __restrict__ wlo,
    const float* __restrict__ qkvb, const float* __restrict__ temp, const float* __restrict__ qe,
    f16* __restrict__ qh_o, f16* __restrict__ ql_o,
    f16* __restrict__ kh_o, f16* __restrict__ kl_o, f16* __restrict__ vt_o)
{
  // LDS image = global_load_lds order: [rowblock][kq*16+row][8] -> frag read is lane-linear b128
  __shared__ __align__(16) f16 Ah[8][64][8];
  __shared__ __align__(16) f16 Al[8][64][8];
  __shared__ __align__(16) f16 Bh[8][64][8];
  __shared__ __align__(16) f16 Bl[8][64][8];
  const int tid = threadIdx.x, lane = tid & 63, w = tid >> 6;
  const int rsel = lane & 15, ksel = lane >> 4;
  const int bx = blockIdx.x & 63, by = blockIdx.x >> 6;
  const int m0 = bx << 7, n0 = by << 7;
  const bool SPLIT = (by < 8);   // Q/K blocks need hi/lo precision; V blocks don't

  const size_t aoff = (size_t)(m0 + w*32 + rsel)*512 + ksel*8;
  const size_t boff = (size_t)(n0 + w*32 + rsel)*512 + ksel*8;
  const f16 *gA0 = xhi + aoff,  *gA1 = gA0 + 16*512;
  const f16 *gAl0 = xlo + aoff, *gAl1 = gAl0 + 16*512;
  const f16 *gB0 = whi + boff,  *gB1 = gB0 + 16*512;
  const f16 *gBl0 = wlo + boff, *gBl1 = gBl0 + 16*512;
  f16 *lA0 = &Ah[2*w][0][0],  *lA1 = &Ah[2*w+1][0][0];
  f16 *lAl0 = &Al[2*w][0][0], *lAl1 = &Al[2*w+1][0][0];
  f16 *lB0 = &Bh[2*w][0][0],  *lB1 = &Bh[2*w+1][0][0];
  f16 *lBl0 = &Bl[2*w][0][0], *lBl1 = &Bl[2*w+1][0][0];

  const f32x4 zero = {0.f, 0.f, 0.f, 0.f};
  f32x4 acc[4][4];
#pragma unroll
  for (int mt = 0; mt < 4; mt++)
#pragma unroll
    for (int nt = 0; nt < 4; nt++) acc[mt][nt] = zero;

  const int mb4 = (w & 1) * 4, nb4 = (w >> 1) * 4;
  for (int k0 = 0; k0 < 512; k0 += 32) {
    __syncthreads();
    gload_lds16(gA0 + k0, lA0);
    gload_lds16(gA1 + k0, lA1);
    gload_lds16(gB0 + k0, lB0);
    gload_lds16(gB1 + k0, lB1);
    if (SPLIT) {
      gload_lds16(gAl0 + k0, lAl0);
      gload_lds16(gAl1 + k0, lAl1);
      gload_lds16(gBl0 + k0, lBl0);
      gload_lds16(gBl1 + k0, lBl1);
    }
    __syncthreads();
    f16x8 bhf[4], blf[4];
#pragma unroll
    for (int nt = 0; nt < 4; nt++) bhf[nt] = ((const f16x8*)&Bh[nb4+nt][0][0])[lane];
    if (SPLIT) {
#pragma unroll
      for (int nt = 0; nt < 4; nt++) blf[nt] = ((const f16x8*)&Bl[nb4+nt][0][0])[lane];
#pragma unroll
      for (int mt = 0; mt < 4; mt++) {
        f16x8 ah = ((const f16x8*)&Ah[mb4+mt][0][0])[lane];
        f16x8 al = ((const f16x8*)&Al[mb4+mt][0][0])[lane];
#pragma unroll
        for (int nt = 0; nt < 4; nt++) {
          acc[mt][nt] = MFMA16(al, bhf[nt], acc[mt][nt]);
          acc[mt][nt] = MFMA16(ah, blf[nt], acc[mt][nt]);
          acc[mt][nt] = MFMA16(ah, bhf[nt], acc[mt][nt]);
        }
      }
    } else {
#pragma unroll
      for (int mt = 0; mt < 4; mt++) {
        f16x8 ah = ((const f16x8*)&Ah[mb4+mt][0][0])[lane];
#pragma unroll
        for (int nt = 0; nt < 4; nt++)
          acc[mt][nt] = MFMA16(ah, bhf[nt], acc[mt][nt]);
      }
    }
  }

  const int mbase = m0 + (w & 1)*64, nbase = n0 + (w >> 1)*64;
  float bc[4];
#pragma unroll
  for (int nt = 0; nt < 4; nt++) bc[nt] = qkvb[nbase + nt*16 + rsel];
#pragma unroll
  for (int mt = 0; mt < 4; mt++)
#pragma unroll
    for (int nt = 0; nt < 4; nt++)
#pragma unroll
      for (int r = 0; r < 4; r++) acc[mt][nt][r] += bc[nt];

  if (by < 8) {   // Q or K: l2-normalize per head-row, write hi/lo
    const bool ISQ = (by < 4);
#pragma unroll
    for (int pair = 0; pair < 2; pair++) {
      const int h = ((nbase - (ISQ ? 0 : 512)) >> 5) + pair;
      float sc = 0.f, qe0 = 0.f, qe1 = 0.f;
      if (ISQ) {
        sc  = log1pf(__expf(temp[h])) * 6.93147180559945f;  // softplus * ln(1024)
        qe0 = qe[h*32 + rsel];
        qe1 = qe[h*32 + 16 + rsel];
      }
      f16* dh = ISQ ? qh_o : kh_o;
      f16* dl = ISQ ? ql_o : kl_o;
#pragma unroll
      for (int mt = 0; mt < 4; mt++) {
        float ss[4];
#pragma unroll
        for (int r = 0; r < 4; r++) {
          float a = acc[mt][2*pair][r], b = acc[mt][2*pair+1][r];
          ss[r] = a*a + b*b;
        }
        for (int s = 1; s < 16; s <<= 1) {
#pragma unroll
          for (int r = 0; r < 4; r++) ss[r] += __shfl_xor(ss[r], s, 64);
        }
#pragma unroll
        for (int r = 0; r < 4; r++) {
          float rn = 1.0f / fmaxf(sqrtf(ss[r]), 1e-12f);
          int m = mbase + mt*16 + ksel*4 + r;
          int b_ = m >> 10, p = m & 1023;
          size_t base = ((size_t)(b_*16 + h)*1024 + p)*32;
          float v0 = acc[mt][2*pair][r] * rn;
          float v1 = acc[mt][2*pair+1][r] * rn;
          if (ISQ) { v0 = (v0 + qe0) * sc; v1 = (v1 + qe1) * sc; }
          f16 h0 = (f16)v0, h1 = (f16)v1;
          dh[base + rsel]      = h0;
          dh[base + 16 + rsel] = h1;
          dl[base + rsel]      = (f16)(v0 - (float)h0);
          dl[base + 16 + rsel] = (f16)(v1 - (float)h1);
        }
      }
    }
  } else {        // V: write transposed [b][h][d][n], 4 rows packed per lane
#pragma unroll
    for (int mt = 0; mt < 4; mt++) {
      int m = mbase + mt*16 + ksel*4;
      int b_ = m >> 10, p = m & 1023;
#pragma unroll
      for (int nt = 0; nt < 4; nt++) {
        int n = nbase + nt*16 + rsel;
        int g = (n - 1024) >> 5, d = n & 31;
        f16x4 pk;
#pragma unroll
        for (int r = 0; r < 4; r++) pk[r] = (f16)acc[mt][nt][r];
        *(f16x4*)(vt_o + ((size_t)(b_*16 + g)*32 + d)*1024 + p) = pk;
      }
    }
  }
}

// ---------------- kernel 5: flash attention (32 Q-rows/wave, no barriers) ----------------
__global__ __launch_bounds__(256) void k_attn(
    const f16* __restrict__ qhi, const f16* __restrict__ qlo,
    const f16* __restrict__ khi, const f16* __restrict__ klo,
    const f16* __restrict__ vt, const f16* __restrict__ bias_sw,
    f16* __restrict__ attnout)
{
  __shared__ __align__(16) f16 Pb[4][16][40];  // per-wave P transpose buffer (pad->80B rows)
  const int tid = threadIdx.x, lane = tid & 63, w = tid >> 6;
  const int rsel = lane & 15, ksel = lane >> 4;
  const int bid = blockIdx.x;
  const int qt = bid & 7, bh = bid >> 3;
  const int h = bh & 15, b = bh >> 4;
  const int q0 = qt*128 + w*32;

  const f16* qh_base = qhi + ((size_t)bh*1024 + q0)*32;
  const f16* ql_base = qlo + ((size_t)bh*1024 + q0)*32;
  f16x8 Qh[2], Ql[2];
#pragma unroll
  for (int rt = 0; rt < 2; rt++) {
    size_t o = (size_t)(rt*16 + rsel)*32 + ksel*8;
    Qh[rt] = *(const f16x8*)(qh_base + o);
    Ql[rt] = *(const f16x8*)(ql_base + o);
  }
  const f16* kh_base = khi + (size_t)bh*32768;
  const f16* kl_base = klo + (size_t)bh*32768;
  const f16* vt_base = vt  + (size_t)bh*32768;
  const f16* bias_base = bias_sw + (size_t)h*1048576 + ((size_t)(q0 >> 2) + ksel)*4096;

  const f32x4 zero = {0.f, 0.f, 0.f, 0.f};
  f32x4 O[2][2];
  float mi[2][4], li[2][4];
#pragma unroll
  for (int rt = 0; rt < 2; rt++) {
    O[rt][0] = zero; O[rt][1] = zero;
#pragma unroll
    for (int r = 0; r < 4; r++) { mi[rt][r] = -3.0e38f; li[rt][r] = 0.f; }
  }
  f16* myP = &Pb[w][0][0];

  for (int m0 = 0; m0 < 1024; m0 += 32) {
    size_t ko = (size_t)(m0 + rsel)*32 + ksel*8;
    f16x8 Kh0 = *(const f16x8*)(kh_base + ko);
    f16x8 Kh1 = *(const f16x8*)(kh_base + ko + 512);
    f16x8 Kl0 = *(const f16x8*)(kl_base + ko);
    f16x8 Kl1 = *(const f16x8*)(kl_base + ko + 512);
    f16x8 V0  = *(const f16x8*)(vt_base + (size_t)rsel*1024 + m0 + ksel*8);
    f16x8 V1  = *(const f16x8*)(vt_base + (size_t)(16 + rsel)*1024 + m0 + ksel*8);
#pragma unroll
    for (int rt = 0; rt < 2; rt++) {
      f32x4 S0 = MFMA16(Ql[rt], Kh0, zero);
      S0 = MFMA16(Qh[rt], Kl0, S0);
      S0 = MFMA16(Qh[rt], Kh0, S0);
      f32x4 S1 = MFMA16(Ql[rt], Kh1, zero);
      S1 = MFMA16(Qh[rt], Kl1, S1);
      S1 = MFMA16(Qh[rt], Kh1, S1);
      f16x4 b0 = *(const f16x4*)(bias_base + (size_t)rt*4*4096 + (size_t)(m0 + rsel)*4);
      f16x4 b1 = *(const f16x4*)(bias_base + (size_t)rt*4*4096 + (size_t)(m0 + 16 + rsel)*4);
      float s0[4], s1[4], cm[4];
#pragma unroll
      for (int r = 0; r < 4; r++) {
        s0[r] = S0[r] + (float)b0[r];
        s1[r] = S1[r] + (float)b1[r];
        cm[r] = fmaxf(s0[r], s1[r]);
      }
      for (int s = 1; s < 16; s <<= 1) {
#pragma unroll
        for (int r = 0; r < 4; r++) cm[r] = fmaxf(cm[r], __shfl_xor(cm[r], s, 64));
      }
      float al[4], rs[4];
#pragma unroll
      for (int r = 0; r < 4; r++) {
        float mn = fmaxf(mi[rt][r], cm[r]);
        al[r] = __expf(mi[rt][r] - mn);
        mi[rt][r] = mn;
        s0[r] = __expf(s0[r] - mn);
        s1[r] = __expf(s1[r] - mn);
        rs[r] = s0[r] + s1[r];
      }
      for (int s = 1; s < 16; s <<= 1) {
#pragma unroll
        for (int r = 0; r < 4; r++) rs[r] += __shfl_xor(rs[r], s, 64);
      }
#pragma unroll
      for (int r = 0; r < 4; r++) {
        li[rt][r] = li[rt][r]*al[r] + rs[r];
        O[rt][0][r] *= al[r];
        O[rt][1][r] *= al[r];
        myP[(ksel*4 + r)*40 + rsel]      = (f16)s0[r];
        myP[(ksel*4 + r)*40 + 16 + rsel] = (f16)s1[r];
      }
      f16x8 Pf = *(const f16x8*)(myP + rsel*40 + ksel*8);  // wave-sync LDS round-trip
      O[rt][0] = MFMA16(Pf, V0, O[rt][0]);
      O[rt][1] = MFMA16(Pf, V1, O[rt][1]);
    }
  }
#pragma unroll
  for (int rt = 0; rt < 2; rt++) {
#pragma unroll
    for (int dt = 0; dt < 2; dt++) {
#pragma unroll
      for (int r = 0; r < 4; r++) {
        int p = q0 + rt*16 + ksel*4 + r;
        float o = O[rt][dt][r] / li[rt][r];
        attnout[((size_t)b*1024 + p)*512 + h*32 + dt*16 + rsel] = (f16)o;
      }
    }
  }
}

// ---------------- kernel 6: proj GEMM f16 -> fp32 out ----------------
__global__ __launch_bounds__(256) void k_proj(
    const f16* __restrict__ A, const f16* __restrict__ Bw,
    const float* __restrict__ pb, float* __restrict__ out)
{
  __shared__ __align__(16) f16 Ah[8][64][8];
  __shared__ __align__(16) f16 Bh[8][64][8];
  const int tid = threadIdx.x, lane = tid & 63, w = tid >> 6;
  const int rsel = lane & 15, ksel = lane >> 4;
  const int bx = blockIdx.x & 63, by = blockIdx.x >> 6;
  const int m0 = bx << 7, n0 = by << 7;
  const f16 *gA0 = A + (size_t)(m0 + w*32 + rsel)*512 + ksel*8,  *gA1 = gA0 + 16*512;
  const f16 *gB0 = Bw + (size_t)(n0 + w*32 + rsel)*512 + ksel*8, *gB1 = gB0 + 16*512;
  f16 *lA0 = &Ah[2*w][0][0], *lA1 = &Ah[2*w+1][0][0];
  f16 *lB0 = &Bh[2*w][0][0], *lB1 = &Bh[2*w+1][0][0];
  const f32x4 zero = {0.f, 0.f, 0.f, 0.f};
  f32x4 acc[4][4];
#pragma unroll
  for (int mt = 0; mt < 4; mt++)
#pragma unroll
    for (int nt = 0; nt < 4; nt++) acc[mt][nt] = zero;
  const int mb4 = (w & 1)*4, nb4 = (w >> 1)*4;
  for (int k0 = 0; k0 < 512; k0 += 32) {
    __syncthreads();
    gload_lds16(gA0 + k0, lA0);
    gload_lds16(gA1 + k0, lA1);
    gload_lds16(gB0 + k0, lB0);
    gload_lds16(gB1 + k0, lB1);
    __syncthreads();
    f16x8 bhf[4];
#pragma unroll
    for (int nt = 0; nt < 4; nt++) bhf[nt] = ((const f16x8*)&Bh[nb4+nt][0][0])[lane];
#pragma unroll
    for (int mt = 0; mt < 4; mt++) {
      f16x8 ah = ((const f16x8*)&Ah[mb4+mt][0][0])[lane];
#pragma unroll
      for (int nt = 0; nt < 4; nt++)
        acc[mt][nt] = MFMA16(ah, bhf[nt], acc[mt][nt]);
    }
  }
  const int mbase = m0 + (w & 1)*64, nbase = n0 + (w >> 1)*64;
  float bc[4];
#pragma unroll
  for (int nt = 0; nt < 4; nt++) bc[nt] = pb[nbase + nt*16 + rsel];
#pragma unroll
  for (int mt = 0; mt < 4; mt++)
#pragma unroll
    for (int nt = 0; nt < 4; nt++)
#pragma unroll
      for (int r = 0; r < 4; r++)
        out[(size_t)(mbase + mt*16 + ksel*4 + r)*512 + nbase + nt*16 + rsel] =
            acc[mt][nt][r] + bc[nt];
}

// ---------------- launch ----------------
extern "C" void kernel_launch(void* const* d_in, const int* in_sizes, int n_in,
                              void* d_out, int out_size, void* d_ws, size_t ws_size,
                              hipStream_t stream) {
  const float* x    = (const float*)d_in[0];
  const int*   rpi  = (const int*)d_in[3];
  const float* rct  = (const float*)d_in[4];
  const float* qw   = (const float*)d_in[5];
  const float* qb   = (const float*)d_in[6];
  const float* pwf  = (const float*)d_in[7];
  const float* pbv  = (const float*)d_in[8];
  const float* temp = (const float*)d_in[9];
  const float* qe   = (const float*)d_in[10];
  const float* f1w  = (const float*)d_in[11];
  const float* f1b  = (const float*)d_in[12];
  const float* f2w  = (const float*)d_in[13];
  const float* f2b  = (const float*)d_in[14];

  char* ws = (char*)d_ws;
  float* t_cpb  = (float*)(ws + OFF_TCPB);
  f16* bias_sw  = (f16*)(ws + OFF_BIAS);
  f16* xhi = (f16*)(ws + OFF_XHI);
  f16* xlo = (f16*)(ws + OFF_XLO);
  f16* whi = (f16*)(ws + OFF_WHI);
  f16* wlo = (f16*)(ws + OFF_WLO);
  f16* pw  = (f16*)(ws + OFF_PW);
  f16* qhi = (f16*)(ws + OFF_QHI);
  f16* qlo = (f16*)(ws + OFF_QLO);
  f16* khi = (f16*)(ws + OFF_KHI);
  f16* klo = (f16*)(ws + OFF_KLO);
  f16* vt  = (f16*)(ws + OFF_VT);
  f16* ao  = (f16*)(ws + OFF_AO);

  k_convert<<<5120, 256, 0, stream>>>(x, qw, pwf, xhi, xlo, whi, wlo, pw);
  k_cpb<<<3969, 64, 0, stream>>>(rct, f1w, f1b, f2w, f2b, t_cpb);
  k_bias<<<4096, 256, 0, stream>>>(rpi, t_cpb, bias_sw);
  k_qkv<<<768, 256, 0, stream>>>(xhi, xlo, whi, wlo, qb, temp, qe,
                                 qhi, qlo, khi, klo, vt);
  k_attn<<<1024, 256, 0, stream>>>(qhi, qlo, khi, klo, vt, bias_sw, ao);
  k_proj<<<256, 256, 0, stream>>>(ao, pw, pbv, (float*)d_out);
}

// Round 2
// 302.614 us; speedup vs baseline: 1.2271x; 1.2271x over previous
//
#include <hip/hip_runtime.h>
#include <cstdint>
#include <cstddef>

typedef _Float16 f16;
typedef _Float16 f16x4 __attribute__((ext_vector_type(4)));
typedef _Float16 f16x8 __attribute__((ext_vector_type(8)));
typedef float f32x4 __attribute__((ext_vector_type(4)));

#define MFMA32(a,b,c) __builtin_amdgcn_mfma_f32_16x16x32_f16((a),(b),(c),0,0,0)
#define MFMA16(a,b,c) __builtin_amdgcn_mfma_f32_16x16x16f16((a),(b),(c),0,0,0)

__device__ __forceinline__ void gload_lds16(const f16* g, f16* l) {
  __builtin_amdgcn_global_load_lds(
      (const __attribute__((address_space(1))) unsigned int*)g,
      (__attribute__((address_space(3))) unsigned int*)l, 16, 0, 0);
}

// ---------------- workspace layout (bytes) ----------------
static constexpr size_t OFF_TCPB = 0;                     // 3969*16*4 fp32
static constexpr size_t OFF_BIAS = 262144;                // 16*1024*1024 f16  [h][m>>2][n][m&3] (m=key,n=query)
static constexpr size_t OFF_XHI  = OFF_BIAS + 33554432;   // 8192*512 f16
static constexpr size_t OFF_XLO  = OFF_XHI + 8388608;
static constexpr size_t OFF_WHI  = OFF_XLO + 8388608;     // 1536*512 f16
static constexpr size_t OFF_WLO  = OFF_WHI + 1572864;
static constexpr size_t OFF_PW   = OFF_WLO + 1572864;     // 512*512 f16
static constexpr size_t OFF_QHI  = OFF_PW  + 524288;      // [B][H][N][32] f16
static constexpr size_t OFF_QLO  = OFF_QHI + 8388608;
static constexpr size_t OFF_KHI  = OFF_QLO + 8388608;
static constexpr size_t OFF_KLO  = OFF_KHI + 8388608;     // (unused this round)
static constexpr size_t OFF_VT   = OFF_KLO + 8388608;     // [B][H][32][N] f16
static constexpr size_t OFF_AO   = OFF_VT  + 8388608;     // [8192][512] f16

// ---------------- kernel 1: fp32 -> f16 hi/lo splits ----------------
__global__ __launch_bounds__(256) void k_convert(
    const float* __restrict__ x, const float* __restrict__ qw, const float* __restrict__ pwf,
    f16* __restrict__ xhi, f16* __restrict__ xlo,
    f16* __restrict__ whi, f16* __restrict__ wlo, f16* __restrict__ pw)
{
  int i = blockIdx.x * 256 + threadIdx.x;
  const float4* src; f16* dh; f16* dl; int j;
  if (i < 1048576)      { j = i;           src = (const float4*)x;   dh = xhi; dl = xlo; }
  else if (i < 1245184) { j = i - 1048576; src = (const float4*)qw;  dh = whi; dl = wlo; }
  else                  { j = i - 1245184; src = (const float4*)pwf; dh = pw;  dl = nullptr; }
  float4 v = src[j];
  f16x4 h;
  h[0] = (f16)v.x; h[1] = (f16)v.y; h[2] = (f16)v.z; h[3] = (f16)v.w;
  ((f16x4*)dh)[j] = h;
  if (dl) {
    f16x4 l;
    l[0] = (f16)(v.x - (float)h[0]); l[1] = (f16)(v.y - (float)h[1]);
    l[2] = (f16)(v.z - (float)h[2]); l[3] = (f16)(v.w - (float)h[3]);
    ((f16x4*)dl)[j] = l;
  }
}

// ---------------- kernel 2: CPB MLP -> t[3969][16] fp32 ----------------
__global__ __launch_bounds__(64) void k_cpb(
    const float* __restrict__ table, const float* __restrict__ w1, const float* __restrict__ b1,
    const float* __restrict__ w2, const float* __restrict__ b2, float* __restrict__ t_out)
{
  const int r = blockIdx.x;
  const int lane = threadIdx.x;
  const float c0 = table[2*r], c1 = table[2*r+1];
  const int j0 = lane * 8;
  float h[8];
#pragma unroll
  for (int jj = 0; jj < 8; jj++) {
    int j = j0 + jj;
    float v = c0 * w1[2*j] + c1 * w1[2*j+1] + b1[j];
    h[jj] = v > 0.0f ? v : 0.0f;
  }
  float acc[16];
#pragma unroll
  for (int o = 0; o < 16; o++) {
    const float4* wp = (const float4*)(w2 + o*512 + j0);
    float4 a = wp[0], bb = wp[1];
    acc[o] = a.x*h[0] + a.y*h[1] + a.z*h[2] + a.w*h[3]
           + bb.x*h[4] + bb.y*h[5] + bb.z*h[6] + bb.w*h[7];
  }
#pragma unroll
  for (int o = 0; o < 16; o++) {
    float v = acc[o];
    for (int s = 1; s < 64; s <<= 1) v += __shfl_xor(v, s, 64);
    acc[o] = v;
  }
  if (lane == 0) {
#pragma unroll
    for (int o = 0; o < 16; o++) t_out[r*16 + o] = acc[o] + b2[o];
  }
}

// ---------------- kernel 3: bias gather -> f16 [h][m>>2][n][m&3]  (m=key, n=query) --------
__global__ __launch_bounds__(256) void k_bias(
    const int* __restrict__ idx, const float* __restrict__ t_cpb, f16* __restrict__ bias_t)
{
  // block: (m4 = bid>>6, ngroup = bid&63); thread: h = t>>4, nl = t&15
  const int m4 = blockIdx.x >> 6, ng = blockIdx.x & 63;
  const int h = threadIdx.x >> 4, nl = threadIdx.x & 15;
  const int n = ng*16 + nl;
  int4 I = *(const int4*)(idx + (size_t)n*1024 + m4*4);
  f16x4 o;
  o[0] = (f16)t_cpb[I.x*16 + h];
  o[1] = (f16)t_cpb[I.y*16 + h];
  o[2] = (f16)t_cpb[I.z*16 + h];
  o[3] = (f16)t_cpb[I.w*16 + h];
  *(f16x4*)(bias_t + (((size_t)h*256 + m4)*1024 + n)*4) = o;
}

// ---------------- kernel 4: QKV GEMM (split f16) + normalize epilogue ----------------
__global__ __launch_bounds__(256) void k_qkv(
    const f16* __restrict__ xhi, const f16* __restrict__ xlo,
    const f16* __restrict__ whi, const f16* __restrict__ wlo,
    const float* __restrict__ qkvb, const float* __restrict__ temp, const float* __restrict__ qe,
    f16* __restrict__ qh_o, f16* __restrict__ ql_o,
    f16* __restrict__ kh_o, f16* __restrict__ vt_o)
{
  __shared__ __align__(16) f16 Ah[8][64][8];
  __shared__ __align__(16) f16 Al[8][64][8];
  __shared__ __align__(16) f16 Bh[8][64][8];
  __shared__ __align__(16) f16 Bl[8][64][8];
  const int tid = threadIdx.x, lane = tid & 63, w = tid >> 6;
  const int rsel = lane & 15, ksel = lane >> 4;
  const int bx = blockIdx.x & 63, by = blockIdx.x >> 6;
  const int m0 = bx << 7, n0 = by << 7;
  const bool SPLIT = (by < 8);

  const size_t aoff = (size_t)(m0 + w*32 + rsel)*512 + ksel*8;
  const size_t boff = (size_t)(n0 + w*32 + rsel)*512 + ksel*8;
  const f16 *gA0 = xhi + aoff,  *gA1 = gA0 + 16*512;
  const f16 *gAl0 = xlo + aoff, *gAl1 = gAl0 + 16*512;
  const f16 *gB0 = whi + boff,  *gB1 = gB0 + 16*512;
  const f16 *gBl0 = wlo + boff, *gBl1 = gBl0 + 16*512;
  f16 *lA0 = &Ah[2*w][0][0],  *lA1 = &Ah[2*w+1][0][0];
  f16 *lAl0 = &Al[2*w][0][0], *lAl1 = &Al[2*w+1][0][0];
  f16 *lB0 = &Bh[2*w][0][0],  *lB1 = &Bh[2*w+1][0][0];
  f16 *lBl0 = &Bl[2*w][0][0], *lBl1 = &Bl[2*w+1][0][0];

  const f32x4 zero = {0.f, 0.f, 0.f, 0.f};
  f32x4 acc[4][4];
#pragma unroll
  for (int mt = 0; mt < 4; mt++)
#pragma unroll
    for (int nt = 0; nt < 4; nt++) acc[mt][nt] = zero;

  const int mb4 = (w & 1) * 4, nb4 = (w >> 1) * 4;
  for (int k0 = 0; k0 < 512; k0 += 32) {
    __syncthreads();
    gload_lds16(gA0 + k0, lA0);
    gload_lds16(gA1 + k0, lA1);
    gload_lds16(gB0 + k0, lB0);
    gload_lds16(gB1 + k0, lB1);
    if (SPLIT) {
      gload_lds16(gAl0 + k0, lAl0);
      gload_lds16(gAl1 + k0, lAl1);
      gload_lds16(gBl0 + k0, lBl0);
      gload_lds16(gBl1 + k0, lBl1);
    }
    __syncthreads();
    f16x8 bhf[4], blf[4];
#pragma unroll
    for (int nt = 0; nt < 4; nt++) bhf[nt] = ((const f16x8*)&Bh[nb4+nt][0][0])[lane];
    if (SPLIT) {
#pragma unroll
      for (int nt = 0; nt < 4; nt++) blf[nt] = ((const f16x8*)&Bl[nb4+nt][0][0])[lane];
#pragma unroll
      for (int mt = 0; mt < 4; mt++) {
        f16x8 ah = ((const f16x8*)&Ah[mb4+mt][0][0])[lane];
        f16x8 al = ((const f16x8*)&Al[mb4+mt][0][0])[lane];
#pragma unroll
        for (int nt = 0; nt < 4; nt++) {
          acc[mt][nt] = MFMA32(al, bhf[nt], acc[mt][nt]);
          acc[mt][nt] = MFMA32(ah, blf[nt], acc[mt][nt]);
          acc[mt][nt] = MFMA32(ah, bhf[nt], acc[mt][nt]);
        }
      }
    } else {
#pragma unroll
      for (int mt = 0; mt < 4; mt++) {
        f16x8 ah = ((const f16x8*)&Ah[mb4+mt][0][0])[lane];
#pragma unroll
        for (int nt = 0; nt < 4; nt++)
          acc[mt][nt] = MFMA32(ah, bhf[nt], acc[mt][nt]);
      }
    }
  }

  const int mbase = m0 + (w & 1)*64, nbase = n0 + (w >> 1)*64;
  float bc[4];
#pragma unroll
  for (int nt = 0; nt < 4; nt++) bc[nt] = qkvb[nbase + nt*16 + rsel];
#pragma unroll
  for (int mt = 0; mt < 4; mt++)
#pragma unroll
    for (int nt = 0; nt < 4; nt++)
#pragma unroll
      for (int r = 0; r < 4; r++) acc[mt][nt][r] += bc[nt];

  if (by < 8) {   // Q or K: l2-normalize per head-row; Q -> hi+lo, K -> hi only
    const bool ISQ = (by < 4);
#pragma unroll
    for (int pair = 0; pair < 2; pair++) {
      const int h = ((nbase - (ISQ ? 0 : 512)) >> 5) + pair;
      float sc = 0.f, qe0 = 0.f, qe1 = 0.f;
      if (ISQ) {
        sc  = log1pf(__expf(temp[h])) * 6.93147180559945f;  // softplus * ln(1024)
        qe0 = qe[h*32 + rsel];
        qe1 = qe[h*32 + 16 + rsel];
      }
      f16* dh = ISQ ? qh_o : kh_o;
#pragma unroll
      for (int mt = 0; mt < 4; mt++) {
        float ss[4];
#pragma unroll
        for (int r = 0; r < 4; r++) {
          float a = acc[mt][2*pair][r], b = acc[mt][2*pair+1][r];
          ss[r] = a*a + b*b;
        }
        for (int s = 1; s < 16; s <<= 1) {
#pragma unroll
          for (int r = 0; r < 4; r++) ss[r] += __shfl_xor(ss[r], s, 64);
        }
#pragma unroll
        for (int r = 0; r < 4; r++) {
          float rn = 1.0f / fmaxf(sqrtf(ss[r]), 1e-12f);
          int m = mbase + mt*16 + ksel*4 + r;
          int b_ = m >> 10, p = m & 1023;
          size_t base = ((size_t)(b_*16 + h)*1024 + p)*32;
          float v0 = acc[mt][2*pair][r] * rn;
          float v1 = acc[mt][2*pair+1][r] * rn;
          if (ISQ) { v0 = (v0 + qe0) * sc; v1 = (v1 + qe1) * sc; }
          f16 h0 = (f16)v0, h1 = (f16)v1;
          dh[base + rsel]      = h0;
          dh[base + 16 + rsel] = h1;
          if (ISQ) {
            ql_o[base + rsel]      = (f16)(v0 - (float)h0);
            ql_o[base + 16 + rsel] = (f16)(v1 - (float)h1);
          }
        }
      }
    }
  } else {        // V: write transposed [b][h][d][n]
#pragma unroll
    for (int mt = 0; mt < 4; mt++) {
      int m = mbase + mt*16 + ksel*4;
      int b_ = m >> 10, p = m & 1023;
#pragma unroll
      for (int nt = 0; nt < 4; nt++) {
        int n = nbase + nt*16 + rsel;
        int g = (n - 1024) >> 5, d = n & 31;
        f16x4 pk;
#pragma unroll
        for (int r = 0; r < 4; r++) pk[r] = (f16)acc[mt][nt][r];
        *(f16x4*)(vt_o + ((size_t)(b_*16 + g)*32 + d)*1024 + p) = pk;
      }
    }
  }
}

// ---------------- kernel 5: flash attention, S^T orientation ----------------
// S^T = K·Q^T (key on ksel*4+r, query on lane&15). Softmax over keys = in-reg + 2 shfl.
// P^T (post-exp S^T) is directly the B-operand of v_mfma_f32_16x16x16_f16 -> O^T = V^T·P^T.
__global__ __launch_bounds__(256, 4) void k_attn(
    const f16* __restrict__ qhi, const f16* __restrict__ qlo,
    const f16* __restrict__ khi, const f16* __restrict__ vt,
    const f16* __restrict__ bias_t, f16* __restrict__ attnout)
{
  __shared__ __align__(16) f16 OT[4][32][40];  // per-wave O^T transpose buffer
  const int lane = threadIdx.x & 63, w = threadIdx.x >> 6;
  const int rsel = lane & 15, ksel = lane >> 4;
  const int bid = blockIdx.x;
  const int qt = bid & 7, bh = bid >> 3;
  const int h = bh & 15, b = bh >> 4;
  const int q0 = qt*128 + w*32;

  f16x8 Qh[2], Ql[2];
#pragma unroll
  for (int c = 0; c < 2; c++) {
    size_t o = ((size_t)bh*1024 + q0 + c*16 + rsel)*32 + ksel*8;
    Qh[c] = *(const f16x8*)(qhi + o);
    Ql[c] = *(const f16x8*)(qlo + o);
  }
  const f16* kh_base = khi + (size_t)bh*32768;
  const f16* vt_base = vt  + (size_t)bh*32768;
  const f16* bias_h  = bias_t + (size_t)h*1048576;

  const f32x4 zero = {0.f, 0.f, 0.f, 0.f};
  f32x4 O[2][2];
  float mi[2], li[2];
#pragma unroll
  for (int c = 0; c < 2; c++) {
    O[c][0] = zero; O[c][1] = zero;
    mi[c] = -3.0e38f; li[c] = 0.f;
  }

  // prefetch K chunk 0
  f16x8 Kh[2];
  Kh[0] = *(const f16x8*)(kh_base + (size_t)(rsel)*32 + ksel*8);
  Kh[1] = *(const f16x8*)(kh_base + (size_t)(16 + rsel)*32 + ksel*8);

  for (int m0 = 0; m0 < 1024; m0 += 32) {
    f16x4 Va[2][2], Bb[2][2];
#pragma unroll
    for (int f = 0; f < 2; f++)
#pragma unroll
      for (int dt = 0; dt < 2; dt++)
        Va[f][dt] = *(const f16x4*)(vt_base + (size_t)(dt*16 + rsel)*1024 + m0 + f*16 + ksel*4);
#pragma unroll
    for (int f = 0; f < 2; f++)
#pragma unroll
      for (int c = 0; c < 2; c++)
        Bb[f][c] = *(const f16x4*)(bias_h + (((size_t)(m0 >> 2) + f*4 + ksel)*1024 + q0 + c*16 + rsel)*4);

    f16x8 Kc0 = Kh[0], Kc1 = Kh[1];
    if (m0 < 992) {
      Kh[0] = *(const f16x8*)(kh_base + (size_t)(m0 + 32 + rsel)*32 + ksel*8);
      Kh[1] = *(const f16x8*)(kh_base + (size_t)(m0 + 48 + rsel)*32 + ksel*8);
    }

    f32x4 St[2][2];
#pragma unroll
    for (int c = 0; c < 2; c++) {
      St[0][c] = MFMA32(Kc0, Ql[c], zero);
      St[0][c] = MFMA32(Kc0, Qh[c], St[0][c]);
      St[1][c] = MFMA32(Kc1, Ql[c], zero);
      St[1][c] = MFMA32(Kc1, Qh[c], St[1][c]);
    }

    f16x4 P16[2][2];
#pragma unroll
    for (int c = 0; c < 2; c++) {
      float s[8];
#pragma unroll
      for (int f = 0; f < 2; f++)
#pragma unroll
        for (int r = 0; r < 4; r++) s[f*4+r] = St[f][c][r] + (float)Bb[f][c][r];
      float cm = s[0];
#pragma unroll
      for (int i = 1; i < 8; i++) cm = fmaxf(cm, s[i]);
      cm = fmaxf(cm, __shfl_xor(cm, 16, 64));
      cm = fmaxf(cm, __shfl_xor(cm, 32, 64));
      float mn = fmaxf(mi[c], cm);
      float alpha = __expf(mi[c] - mn);
      mi[c] = mn;
      float p[8], rs = 0.f;
#pragma unroll
      for (int i = 0; i < 8; i++) { p[i] = __expf(s[i] - mn); rs += p[i]; }
      rs += __shfl_xor(rs, 16, 64);
      rs += __shfl_xor(rs, 32, 64);
      li[c] = li[c]*alpha + rs;
#pragma unroll
      for (int dt = 0; dt < 2; dt++)
#pragma unroll
        for (int r = 0; r < 4; r++) O[c][dt][r] *= alpha;
#pragma unroll
      for (int f = 0; f < 2; f++)
#pragma unroll
        for (int r = 0; r < 4; r++) P16[f][c][r] = (f16)p[f*4+r];
    }
#pragma unroll
    for (int c = 0; c < 2; c++)
#pragma unroll
      for (int dt = 0; dt < 2; dt++) {
        O[c][dt] = MFMA16(Va[0][dt], P16[0][c], O[c][dt]);
        O[c][dt] = MFMA16(Va[1][dt], P16[1][c], O[c][dt]);
      }
  }

  // epilogue: O^T -> LDS transpose -> coalesced store (wave-synchronous)
#pragma unroll
  for (int c = 0; c < 2; c++) {
    float inv = 1.0f / li[c];
#pragma unroll
    for (int dt = 0; dt < 2; dt++)
#pragma unroll
      for (int r = 0; r < 4; r++)
        OT[w][c*16 + rsel][dt*16 + ksel*4 + r] = (f16)(O[c][dt][r] * inv);
  }
  int row = lane >> 1, half = lane & 1;
  f16x8 o0 = *(const f16x8*)(&OT[w][row][half*16]);
  f16x8 o1 = *(const f16x8*)(&OT[w][row][half*16 + 8]);
  f16* outp = attnout + ((size_t)b*1024 + q0 + row)*512 + h*32 + half*16;
  *(f16x8*)outp = o0;
  *(f16x8*)(outp + 8) = o1;
}

// ---------------- kernel 6: proj GEMM f16 -> fp32 out ----------------
__global__ __launch_bounds__(256) void k_proj(
    const f16* __restrict__ A, const f16* __restrict__ Bw,
    const float* __restrict__ pb, float* __restrict__ out)
{
  __shared__ __align__(16) f16 Ah[8][64][8];
  __shared__ __align__(16) f16 Bh[8][64][8];
  const int tid = threadIdx.x, lane = tid & 63, w = tid >> 6;
  const int rsel = lane & 15, ksel = lane >> 4;
  const int bx = blockIdx.x & 63, by = blockIdx.x >> 6;
  const int m0 = bx << 7, n0 = by << 7;
  const f16 *gA0 = A + (size_t)(m0 + w*32 + rsel)*512 + ksel*8,  *gA1 = gA0 + 16*512;
  const f16 *gB0 = Bw + (size_t)(n0 + w*32 + rsel)*512 + ksel*8, *gB1 = gB0 + 16*512;
  f16 *lA0 = &Ah[2*w][0][0], *lA1 = &Ah[2*w+1][0][0];
  f16 *lB0 = &Bh[2*w][0][0], *lB1 = &Bh[2*w+1][0][0];
  const f32x4 zero = {0.f, 0.f, 0.f, 0.f};
  f32x4 acc[4][4];
#pragma unroll
  for (int mt = 0; mt < 4; mt++)
#pragma unroll
    for (int nt = 0; nt < 4; nt++) acc[mt][nt] = zero;
  const int mb4 = (w & 1)*4, nb4 = (w >> 1)*4;
  for (int k0 = 0; k0 < 512; k0 += 32) {
    __syncthreads();
    gload_lds16(gA0 + k0, lA0);
    gload_lds16(gA1 + k0, lA1);
    gload_lds16(gB0 + k0, lB0);
    gload_lds16(gB1 + k0, lB1);
    __syncthreads();
    f16x8 bhf[4];
#pragma unroll
    for (int nt = 0; nt < 4; nt++) bhf[nt] = ((const f16x8*)&Bh[nb4+nt][0][0])[lane];
#pragma unroll
    for (int mt = 0; mt < 4; mt++) {
      f16x8 ah = ((const f16x8*)&Ah[mb4+mt][0][0])[lane];
#pragma unroll
      for (int nt = 0; nt < 4; nt++)
        acc[mt][nt] = MFMA32(ah, bhf[nt], acc[mt][nt]);
    }
  }
  const int mbase = m0 + (w & 1)*64, nbase = n0 + (w >> 1)*64;
  float bc[4];
#pragma unroll
  for (int nt = 0; nt < 4; nt++) bc[nt] = pb[nbase + nt*16 + rsel];
#pragma unroll
  for (int mt = 0; mt < 4; mt++)
#pragma unroll
    for (int nt = 0; nt < 4; nt++)
#pragma unroll
      for (int r = 0; r < 4; r++)
        out[(size_t)(mbase + mt*16 + ksel*4 + r)*512 + nbase + nt*16 + rsel] =
            acc[mt][nt][r] + bc[nt];
}

// ---------------- launch ----------------
extern "C" void kernel_launch(void* const* d_in, const int* in_sizes, int n_in,
                              void* d_out, int out_size, void* d_ws, size_t ws_size,
                              hipStream_t stream) {
  const float* x    = (const float*)d_in[0];
  const int*   rpi  = (const int*)d_in[3];
  const float* rct  = (const float*)d_in[4];
  const float* qw   = (const float*)d_in[5];
  const float* qb   = (const float*)d_in[6];
  const float* pwf  = (const float*)d_in[7];
  const float* pbv  = (const float*)d_in[8];
  const float* temp = (const float*)d_in[9];
  const float* qe   = (const float*)d_in[10];
  const float* f1w  = (const float*)d_in[11];
  const float* f1b  = (const float*)d_in[12];
  const float* f2w  = (const float*)d_in[13];
  const float* f2b  = (const float*)d_in[14];

  char* ws = (char*)d_ws;
  float* t_cpb  = (float*)(ws + OFF_TCPB);
  f16* bias_t   = (f16*)(ws + OFF_BIAS);
  f16* xhi = (f16*)(ws + OFF_XHI);
  f16* xlo = (f16*)(ws + OFF_XLO);
  f16* whi = (f16*)(ws + OFF_WHI);
  f16* wlo = (f16*)(ws + OFF_WLO);
  f16* pw  = (f16*)(ws + OFF_PW);
  f16* qhi = (f16*)(ws + OFF_QHI);
  f16* qlo = (f16*)(ws + OFF_QLO);
  f16* khi = (f16*)(ws + OFF_KHI);
  f16* vt  = (f16*)(ws + OFF_VT);
  f16* ao  = (f16*)(ws + OFF_AO);

  k_convert<<<5120, 256, 0, stream>>>(x, qw, pwf, xhi, xlo, whi, wlo, pw);
  k_cpb<<<3969, 64, 0, stream>>>(rct, f1w, f1b, f2w, f2b, t_cpb);
  k_bias<<<16384, 256, 0, stream>>>(rpi, t_cpb, bias_t);
  k_qkv<<<768, 256, 0, stream>>>(xhi, xlo, whi, wlo, qb, temp, qe,
                                 qhi, qlo, khi, vt);
  k_attn<<<1024, 256, 0, stream>>>(qhi, qlo, khi, vt, bias_t, ao);
  k_proj<<<256, 256, 0, stream>>>(ao, pw, pbv, (float*)d_out);
}